// Round 2
// baseline (325.214 us; speedup 1.0000x reference)
//
#include <hip/hip_runtime.h>

typedef unsigned short u16;
typedef unsigned int   u32;
typedef short bf16x8 __attribute__((ext_vector_type(8)));
typedef float f32x2  __attribute__((ext_vector_type(2)));
typedef float f32x4  __attribute__((ext_vector_type(4)));
typedef float f32x16 __attribute__((ext_vector_type(16)));

#define NB  32
#define NQ  1024
#define GS  1024
#define NH  8
#define SCQ (0.25f * 1.4426950408889634f)   /* 1/sqrt(16) * log2(e) */
#define MBIG (-1.0e30f)

#define MFMA16(a, b, c) __builtin_amdgcn_mfma_f32_16x16x32_bf16(a, b, c, 0, 0, 0)
#define MFMA32(a, b, c) __builtin_amdgcn_mfma_f32_32x32x16_bf16(a, b, c, 0, 0, 0)

__device__ __forceinline__ u16 f2bf(float f) {  // RNE float->bf16 bits
    u32 u = __float_as_uint(f);
    return (u16)((u + 0x7fffu + ((u >> 16) & 1u)) >> 16);
}
// packed round-half-up: result = bf(a) | bf(b)<<16, 3 VALU ops via v_perm_b32
__device__ __forceinline__ u32 pk2bf(float a, float b) {
    u32 ua = __float_as_uint(a) + 0x8000u;
    u32 ub = __float_as_uint(b) + 0x8000u;
    return __builtin_amdgcn_perm(ub, ua, 0x07060302u);  // bytes [b3 b2 a3 a2]
}

// ---------------------------------------------------------------------------
// Weight prep (256 blocks, 1 elem/thread): Wp[m][i] bf16.
//  m=0..2 (Wq/Wk/Wv [8][128][16]): i = col*128 + k, col=16h+e, k=d; SCQ in m=0.
//  m=3 (Wout [8][16][128]):        i = d*128 + he   (Wob layout for fused out).
// ---------------------------------------------------------------------------
__global__ __launch_bounds__(256) void wprep(const float* __restrict__ Wq,
                                             const float* __restrict__ Wk,
                                             const float* __restrict__ Wv,
                                             const float* __restrict__ Wout,
                                             u16* __restrict__ Wp) {
    int g = blockIdx.x * 256 + threadIdx.x;   // 65536 total
    int m = g >> 14;
    int i = g & 16383;
    const float* src = (m == 0) ? Wq : (m == 1) ? Wk : (m == 2) ? Wv : Wout;
    float sc = (m == 0) ? SCQ : 1.0f;
    float v;
    if (m < 3) { int cc = i >> 7, k = i & 127;  v = src[(cc >> 4) * 2048 + k * 16 + (cc & 15)]; }
    else       { int d  = i >> 7, he = i & 127; v = src[(he >> 4) * 2048 + (he & 15) * 128 + d]; }
    Wp[m * 16384 + i] = f2bf(v * sc);
}

// ---------------------------------------------------------------------------
// MFMA GEMM: C[128x128] = A[128x128] * W^T, K=128 staged once.
// 256 thr = 4 waves; A fp32 -> bf16 in staging; W prepped bf16 (b128 copies).
// Epilogue goes through LDS (reusing As) so ALL global stores are int4:
// MODE 0: bf16 out row-major.
// MODE 2: bf16 out transposed per batch, NATURAL token order:
//         Vt_g[b][col][tb]  (flash stages V tiles by straight int4 copy).
// ---------------------------------------------------------------------------
template <int MODE>
__device__ __forceinline__ void mgemm(const float* __restrict__ Ain,
                                      const u16* __restrict__ Wpm,
                                      u16* __restrict__ outb,
                                      u16* As, u16* Ws, int row0) {
    const int t    = threadIdx.x;
    const int wv   = t >> 6;
    const int lane = t & 63;
    const int quad = lane >> 4;
    const int c    = lane & 15;

#pragma unroll
    for (int g0 = 0; g0 < 2048; g0 += 256) {
        int g = g0 + t;
        int row = g >> 4, k0 = (g & 15) * 8;
        const float4* ap = (const float4*)&Ain[(size_t)(row0 + row) * 128 + k0];
        float4 a0 = ap[0], a1 = ap[1];
        int4 pk;
        pk.x = (int)pk2bf(a0.x, a0.y);
        pk.y = (int)pk2bf(a0.z, a0.w);
        pk.z = (int)pk2bf(a1.x, a1.y);
        pk.w = (int)pk2bf(a1.z, a1.w);
        *(int4*)&As[row * 136 + k0] = pk;
    }
#pragma unroll
    for (int g0 = 0; g0 < 2048; g0 += 256) {
        int g = g0 + t;
        int cc = g >> 4, k0 = (g & 15) * 8;
        *(int4*)&Ws[cc * 136 + k0] = *(const int4*)&Wpm[cc * 128 + k0];
    }
    __syncthreads();

    const f32x4 zf = {0.f, 0.f, 0.f, 0.f};
    f32x4 acc[2][8];
#pragma unroll
    for (int s = 0; s < 2; ++s)
#pragma unroll
        for (int j = 0; j < 8; ++j) acc[s][j] = zf;

#pragma unroll
    for (int kt = 0; kt < 4; ++kt) {
        bf16x8 af0 = *(const bf16x8*)&As[(wv * 32 + c) * 136 + kt * 32 + quad * 8];
        bf16x8 af1 = *(const bf16x8*)&As[(wv * 32 + 16 + c) * 136 + kt * 32 + quad * 8];
#pragma unroll
        for (int j = 0; j < 8; ++j) {
            bf16x8 bfr = *(const bf16x8*)&Ws[(j * 16 + c) * 136 + kt * 32 + quad * 8];
            acc[0][j] = MFMA16(af0, bfr, acc[0][j]);
            acc[1][j] = MFMA16(af1, bfr, acc[1][j]);
        }
    }

    // ---- epilogue via LDS: scatter bf16 into As, then coalesced int4 out ----
    __syncthreads();                 // all As/Ws reads complete
    u16* Os = As;                    // reuse 128x136 u16
#pragma unroll
    for (int s = 0; s < 2; ++s)
#pragma unroll
        for (int j = 0; j < 8; ++j)
#pragma unroll
            for (int r = 0; r < 4; ++r) {
                int lrow = wv * 32 + s * 16 + quad * 4 + r;
                int col  = j * 16 + c;
                u16 v = f2bf(acc[s][j][r]);
                if (MODE == 0) {
                    Os[lrow * 136 + col] = v;
                } else {
                    Os[col * 136 + lrow] = v;   // natural token order
                }
            }
    __syncthreads();

    if (MODE == 0) {
#pragma unroll
        for (int it = 0; it < 8; ++it) {
            int chunk = it * 256 + t;           // 2048 int4 chunks
            int lrow = chunk >> 4, c0 = (chunk & 15) * 8;
            *(int4*)&outb[(size_t)(row0 + lrow) * 128 + c0] =
                *(const int4*)&Os[lrow * 136 + c0];
        }
    } else {
        int bI = row0 >> 10, tb0 = row0 & 1023; // 128-aligned
#pragma unroll
        for (int it = 0; it < 8; ++it) {
            int chunk = it * 256 + t;
            int col = chunk >> 4, t0 = (chunk & 15) * 8;
            *(int4*)&outb[(size_t)bI * (128 * 1024) + (size_t)col * 1024 + tb0 + t0] =
                *(const int4*)&Os[col * 136 + t0];
        }
    }
}

__global__ __launch_bounds__(256, 2) void proj_mfma(const float* __restrict__ q,
                                                    const float* __restrict__ h,
                                                    const u16* __restrict__ Wp,
                                                    u16* __restrict__ Qb,
                                                    u16* __restrict__ Kb,
                                                    u16* __restrict__ Vtg) {
    __shared__ u16 As[128 * 136];
    __shared__ u16 Ws[128 * 136];
    int row0 = blockIdx.x * 128;
    if (blockIdx.y == 0)      mgemm<0>(q, Wp,         Qb,  As, Ws, row0);
    else if (blockIdx.y == 1) mgemm<0>(h, Wp + 16384, Kb,  As, Ws, row0);
    else                      mgemm<2>(h, Wp + 32768, Vtg, As, Ws, row0);
}

// ---------------------------------------------------------------------------
// MFMA flash attention + fused out-projection, v2 (swapped 32x32x16 scores).
// Block = (batch, 32 q-rows), 512 thr = 8 waves = 8 heads.
// Score: D[key][q] = MFMA32(K_frag, Q_frag, C) with K=16 = exact head dim
//   (no zero-padded K half). C pre-loaded with mask addend {0,-1e30} from
//   Mf[q][key] (natural orientation, no bit-permute).
// Softmax: raw v_exp_f32 via __builtin_amdgcn_exp2f (exp2f would expand to
//   the denormal-safe multi-instruction form — the round-1 VALU hog).
//   exp2(-1e30) underflows to exactly 0 -> masked contributions vanish.
// P repack: lane holds P[16 keys][q]; pack pairs -> 4x ds_write_b64 into
//   Ps[q][key] (natural key order), PV = 2x 16x16x32 as before.
// LDS: 8704+9216+18432+4608 = 40960 B exactly -> 4 blocks/CU.
// ---------------------------------------------------------------------------
__global__ __launch_bounds__(512, 8) void flash_mfma(const u16* __restrict__ Qb,
                                                     const u16* __restrict__ Kb,
                                                     const u16* __restrict__ Vtg,
                                                     const int* __restrict__ mask,
                                                     const u16* __restrict__ Wob,
                                                     float* __restrict__ out) {
    __shared__ u16 Kt[32 * 136];        // [key][dim]; reused as Hs after loop
    __shared__ u16 Vtt[128 * 36];       // [dim][key] natural
    __shared__ u16 Ps[NH][32 * 36];     // per-wave P [q][key] natural
    __shared__ float Mf[32 * 36];       // mask addend [q][key], stride 36

    const int b    = blockIdx.x;
    const int q0   = blockIdx.y * 32;
    const int t    = threadIdx.x;
    const int hh   = t >> 6;
    const int lane = t & 63;
    const int quad = lane >> 4;         // 0..3
    const int c    = lane & 15;
    const int qq   = lane & 31;         // score col (q-row) / A-frag row (key)
    const int hi   = lane >> 5;         // k-slice select for 32x32x16 frags

    const f32x4 zf = {0.f, 0.f, 0.f, 0.f};

    // Q fragment (B operand of swapped score MFMA): full 16-dim head slice
    bf16x8 qf = *(const bf16x8*)&Qb[((size_t)b * NQ + q0 + qq) * 128 +
                                    hh * 16 + hi * 8];

    f32x4 O[2] = {zf, zf};
    float lsum = 0.f;

    // staging indices
    const int skey = t >> 4;            // K: key 0..31, dim octet (t&15)*8
    const int sd0  = (t & 15) * 8;
    const int vdim = t >> 2;            // V: dim 0..127, slot octet (t&3)*8
    const int vs0  = (t & 3) * 8;
    const int mrow = t >> 4;            // M: q-row 0..31, key pair (t&15)*2
    const int mk0  = (t & 15) * 2;

    const u16* Kptr = &Kb[((size_t)b * GS + skey) * 128 + sd0];
    const u16* Vptr = &Vtg[(size_t)b * (128 * 1024) + (size_t)vdim * 1024 + vs0];
    const int* Mptr = &mask[((size_t)b * NQ + q0 + mrow) * GS + mk0];

    int4 kreg = *(const int4*)Kptr;
    int4 vreg = *(const int4*)Vptr;
    int2 mreg = *(const int2*)Mptr;

    for (int g0 = 0; g0 < GS; g0 += 32) {
        __syncthreads();
        *(int4*)&Kt[skey * 136 + sd0] = kreg;
        *(int4*)&Vtt[vdim * 36 + vs0] = vreg;
        f32x2 mm;
        mm.x = mreg.x ? MBIG : 0.f;
        mm.y = mreg.y ? MBIG : 0.f;
        *(f32x2*)&Mf[mrow * 36 + mk0] = mm;
        __syncthreads();

        if (g0 + 32 < GS) {
            Kptr += 32 * 128;  kreg = *(const int4*)Kptr;
            Vptr += 32;        vreg = *(const int4*)Vptr;
            Mptr += 32;        mreg = *(const int2*)Mptr;
        }

        // swapped score: D[key][q], K=16 (head dim), mask addend in C
        bf16x8 kf = *(const bf16x8*)&Kt[qq * 136 + hh * 16 + hi * 8];
        f32x16 c0;
#pragma unroll
        for (int blk = 0; blk < 4; ++blk) {
            f32x4 m = *(const f32x4*)&Mf[qq * 36 + 8 * blk + 4 * hi];
            c0[4 * blk + 0] = m.x;
            c0[4 * blk + 1] = m.y;
            c0[4 * blk + 2] = m.z;
            c0[4 * blk + 3] = m.w;
        }
        f32x16 sc = MFMA32(kf, qf, c0);

        bf16x8 vf = *(const bf16x8*)&Vtt[(hh * 16 + c) * 36 + quad * 8];

        // softmax numerators: raw v_exp_f32; masked -> exactly 0
        float e[16];
#pragma unroll
        for (int r = 0; r < 16; ++r) e[r] = __builtin_amdgcn_exp2f(sc[r]);
        lsum += ((e[0] + e[1]) + (e[2] + e[3])) + ((e[4] + e[5]) + (e[6] + e[7])) +
                (((e[8] + e[9]) + (e[10] + e[11])) + ((e[12] + e[13]) + (e[14] + e[15])));
        // reg r -> key (r&3) + 8*(r>>2) + 4*hi ; pack 4 keys per b64 write
#pragma unroll
        for (int blk = 0; blk < 4; ++blk) {
            int2 pw;
            pw.x = (int)pk2bf(e[4 * blk + 0], e[4 * blk + 1]);
            pw.y = (int)pk2bf(e[4 * blk + 2], e[4 * blk + 3]);
            *(int2*)&Ps[hh][qq * 36 + 8 * blk + 4 * hi] = pw;
        }

        // PV in natural key order
#pragma unroll
        for (int s = 0; s < 2; ++s) {
            bf16x8 pf = *(const bf16x8*)&Ps[hh][(s * 16 + c) * 36 + quad * 8];
            O[s] = MFMA16(pf, vf, O[s]);
        }
    }

    // l-reduction: lane qq holds half-sum for q-row qq; combine halves
    lsum += __shfl_xor(lsum, 32);
    float rlv = (lsum > 0.f) ? 1.f / lsum : 0.f;

    __syncthreads();
    u16* Hs = Kt;
#pragma unroll
    for (int s = 0; s < 2; ++s)
#pragma unroll
        for (int r = 0; r < 4; ++r) {
            float rlq = __shfl(rlv, s * 16 + quad * 4 + r);
            Hs[(s * 16 + quad * 4 + r) * 136 + hh * 16 + c] =
                f2bf(O[s][r] * rlq);
        }
    __syncthreads();

    // fused out-projection: wave hh computes out cols hh*16..+15
    f32x4 oacc[2] = {zf, zf};
#pragma unroll
    for (int kt = 0; kt < 4; ++kt) {
        bf16x8 bfr = *(const bf16x8*)&Wob[(hh * 16 + c) * 128 + kt * 32 + quad * 8];
#pragma unroll
        for (int s = 0; s < 2; ++s) {
            bf16x8 af = *(const bf16x8*)&Hs[(s * 16 + c) * 136 + kt * 32 + quad * 8];
            oacc[s] = MFMA16(af, bfr, oacc[s]);
        }
    }
#pragma unroll
    for (int s = 0; s < 2; ++s)
#pragma unroll
        for (int r = 0; r < 4; ++r)
            out[((size_t)b * NQ + q0 + s * 16 + quad * 4 + r) * 128 + hh * 16 + c] =
                oacc[s][r];
}

extern "C" void kernel_launch(void* const* d_in, const int* in_sizes, int n_in,
                              void* d_out, int out_size, void* d_ws, size_t ws_size,
                              hipStream_t stream) {
    const float* q    = (const float*)d_in[0];
    const float* h    = (const float*)d_in[1];
    const int*   mask = (const int*)d_in[2];
    const float* Wq   = (const float*)d_in[3];
    const float* Wk   = (const float*)d_in[4];
    const float* Wv   = (const float*)d_in[5];
    const float* Wout = (const float*)d_in[6];
    float* out = (float*)d_out;

    const size_t NTOK = (size_t)NB * NQ;     // 32768
    u16* Qb  = (u16*)d_ws;                   // 8 MB each
    u16* Kb  = Qb + NTOK * 128;
    u16* Vtg = Kb + NTOK * 128;              // V transposed per batch (natural)
    u16* Wp  = Vtg + NTOK * 128;             // prepped weights (incl. Wob), 128 KB

    wprep<<<dim3(256), 256, 0, stream>>>(Wq, Wk, Wv, Wout, Wp);
    proj_mfma<<<dim3(256, 3), 256, 0, stream>>>(q, h, Wp, Qb, Kb, Vtg);
    flash_mfma<<<dim3(NB, NQ / 32), 512, 0, stream>>>(Qb, Kb, Vtg, mask,
                                                      Wp + 49152, out);
}

// Round 3
// 306.657 us; speedup vs baseline: 1.0605x; 1.0605x over previous
//
#include <hip/hip_runtime.h>

typedef unsigned short u16;
typedef unsigned int   u32;
typedef short bf16x8 __attribute__((ext_vector_type(8)));
typedef float f32x2  __attribute__((ext_vector_type(2)));
typedef float f32x4  __attribute__((ext_vector_type(4)));
typedef float f32x16 __attribute__((ext_vector_type(16)));

#define NB  32
#define NQ  1024
#define GS  1024
#define NH  8
#define SCQ (0.25f * 1.4426950408889634f)   /* 1/sqrt(16) * log2(e) */
#define MBIG (-1.0e30f)

#define MFMA16(a, b, c) __builtin_amdgcn_mfma_f32_16x16x32_bf16(a, b, c, 0, 0, 0)
#define MFMA32(a, b, c) __builtin_amdgcn_mfma_f32_32x32x16_bf16(a, b, c, 0, 0, 0)

__device__ __forceinline__ u16 f2bf(float f) {  // RNE float->bf16 bits
    u32 u = __float_as_uint(f);
    return (u16)((u + 0x7fffu + ((u >> 16) & 1u)) >> 16);
}
// packed round-half-up: result = bf(a) | bf(b)<<16, 3 VALU ops via v_perm_b32
__device__ __forceinline__ u32 pk2bf(float a, float b) {
    u32 ua = __float_as_uint(a) + 0x8000u;
    u32 ub = __float_as_uint(b) + 0x8000u;
    return __builtin_amdgcn_perm(ub, ua, 0x07060302u);  // bytes [b3 b2 a3 a2]
}

// ---------------------------------------------------------------------------
// Weight prep (256 blocks, 1 elem/thread): Wp[m][i] bf16.
//  m=0..2 (Wq/Wk/Wv [8][128][16]): i = col*128 + k, col=16h+e, k=d; SCQ in m=0.
//  m=3 (Wout [8][16][128]):        i = d*128 + he   (Wob layout for fused out).
// ---------------------------------------------------------------------------
__global__ __launch_bounds__(256) void wprep(const float* __restrict__ Wq,
                                             const float* __restrict__ Wk,
                                             const float* __restrict__ Wv,
                                             const float* __restrict__ Wout,
                                             u16* __restrict__ Wp) {
    int g = blockIdx.x * 256 + threadIdx.x;   // 65536 total
    int m = g >> 14;
    int i = g & 16383;
    const float* src = (m == 0) ? Wq : (m == 1) ? Wk : (m == 2) ? Wv : Wout;
    float sc = (m == 0) ? SCQ : 1.0f;
    float v;
    if (m < 3) { int cc = i >> 7, k = i & 127;  v = src[(cc >> 4) * 2048 + k * 16 + (cc & 15)]; }
    else       { int d  = i >> 7, he = i & 127; v = src[(he >> 4) * 2048 + (he & 15) * 128 + d]; }
    Wp[m * 16384 + i] = f2bf(v * sc);
}

// ---------------------------------------------------------------------------
// MFMA GEMM: C[128x128] = A[128x128] * W^T, K=128 staged once.
// 256 thr = 4 waves; A fp32 -> bf16 in staging; W prepped bf16 (b128 copies).
// Epilogue goes through LDS (reusing As) so ALL global stores are int4:
// MODE 0: bf16 out row-major.
// MODE 2: bf16 out transposed per batch, NATURAL token order:
//         Vt_g[b][col][tb]  (flash stages V tiles by straight int4 copy).
// ---------------------------------------------------------------------------
template <int MODE>
__device__ __forceinline__ void mgemm(const float* __restrict__ Ain,
                                      const u16* __restrict__ Wpm,
                                      u16* __restrict__ outb,
                                      u16* As, u16* Ws, int row0) {
    const int t    = threadIdx.x;
    const int wv   = t >> 6;
    const int lane = t & 63;
    const int quad = lane >> 4;
    const int c    = lane & 15;

#pragma unroll
    for (int g0 = 0; g0 < 2048; g0 += 256) {
        int g = g0 + t;
        int row = g >> 4, k0 = (g & 15) * 8;
        const float4* ap = (const float4*)&Ain[(size_t)(row0 + row) * 128 + k0];
        float4 a0 = ap[0], a1 = ap[1];
        int4 pk;
        pk.x = (int)pk2bf(a0.x, a0.y);
        pk.y = (int)pk2bf(a0.z, a0.w);
        pk.z = (int)pk2bf(a1.x, a1.y);
        pk.w = (int)pk2bf(a1.z, a1.w);
        *(int4*)&As[row * 136 + k0] = pk;
    }
#pragma unroll
    for (int g0 = 0; g0 < 2048; g0 += 256) {
        int g = g0 + t;
        int cc = g >> 4, k0 = (g & 15) * 8;
        *(int4*)&Ws[cc * 136 + k0] = *(const int4*)&Wpm[cc * 128 + k0];
    }
    __syncthreads();

    const f32x4 zf = {0.f, 0.f, 0.f, 0.f};
    f32x4 acc[2][8];
#pragma unroll
    for (int s = 0; s < 2; ++s)
#pragma unroll
        for (int j = 0; j < 8; ++j) acc[s][j] = zf;

#pragma unroll
    for (int kt = 0; kt < 4; ++kt) {
        bf16x8 af0 = *(const bf16x8*)&As[(wv * 32 + c) * 136 + kt * 32 + quad * 8];
        bf16x8 af1 = *(const bf16x8*)&As[(wv * 32 + 16 + c) * 136 + kt * 32 + quad * 8];
#pragma unroll
        for (int j = 0; j < 8; ++j) {
            bf16x8 bfr = *(const bf16x8*)&Ws[(j * 16 + c) * 136 + kt * 32 + quad * 8];
            acc[0][j] = MFMA16(af0, bfr, acc[0][j]);
            acc[1][j] = MFMA16(af1, bfr, acc[1][j]);
        }
    }

    // ---- epilogue via LDS: scatter bf16 into As, then coalesced int4 out ----
    __syncthreads();                 // all As/Ws reads complete
    u16* Os = As;                    // reuse 128x136 u16
#pragma unroll
    for (int s = 0; s < 2; ++s)
#pragma unroll
        for (int j = 0; j < 8; ++j)
#pragma unroll
            for (int r = 0; r < 4; ++r) {
                int lrow = wv * 32 + s * 16 + quad * 4 + r;
                int col  = j * 16 + c;
                u16 v = f2bf(acc[s][j][r]);
                if (MODE == 0) {
                    Os[lrow * 136 + col] = v;
                } else {
                    Os[col * 136 + lrow] = v;   // natural token order
                }
            }
    __syncthreads();

    if (MODE == 0) {
#pragma unroll
        for (int it = 0; it < 8; ++it) {
            int chunk = it * 256 + t;           // 2048 int4 chunks
            int lrow = chunk >> 4, c0 = (chunk & 15) * 8;
            *(int4*)&outb[(size_t)(row0 + lrow) * 128 + c0] =
                *(const int4*)&Os[lrow * 136 + c0];
        }
    } else {
        int bI = row0 >> 10, tb0 = row0 & 1023; // 128-aligned
#pragma unroll
        for (int it = 0; it < 8; ++it) {
            int chunk = it * 256 + t;
            int col = chunk >> 4, t0 = (chunk & 15) * 8;
            *(int4*)&outb[(size_t)bI * (128 * 1024) + (size_t)col * 1024 + tb0 + t0] =
                *(const int4*)&Os[col * 136 + t0];
        }
    }
}

__global__ __launch_bounds__(256, 2) void proj_mfma(const float* __restrict__ q,
                                                    const float* __restrict__ h,
                                                    const u16* __restrict__ Wp,
                                                    u16* __restrict__ Qb,
                                                    u16* __restrict__ Kb,
                                                    u16* __restrict__ Vtg) {
    __shared__ u16 As[128 * 136];
    __shared__ u16 Ws[128 * 136];
    int row0 = blockIdx.x * 128;
    if (blockIdx.y == 0)      mgemm<0>(q, Wp,         Qb,  As, Ws, row0);
    else if (blockIdx.y == 1) mgemm<0>(h, Wp + 16384, Kb,  As, Ws, row0);
    else                      mgemm<2>(h, Wp + 32768, Vtg, As, Ws, row0);
}

// ---------------------------------------------------------------------------
// MFMA flash attention + fused out-projection, v3.
// v2 structure (swapped 32x32x16 scores, raw v_exp_f32, natural key order)
// but __launch_bounds__(512, 4): v2's (512,8) capped the register budget
// below the ~100-VGPR live set (f32x16 score acc + e[16] + staging) and
// spilled the hot loop to scratch — WRITE_SIZE 16.4->36.9 MB was the tell.
// LDS: 8704+9216+18432+4608 = 40960 B.
// ---------------------------------------------------------------------------
__global__ __launch_bounds__(512, 4) void flash_mfma(const u16* __restrict__ Qb,
                                                     const u16* __restrict__ Kb,
                                                     const u16* __restrict__ Vtg,
                                                     const int* __restrict__ mask,
                                                     const u16* __restrict__ Wob,
                                                     float* __restrict__ out) {
    __shared__ u16 Kt[32 * 136];        // [key][dim]; reused as Hs after loop
    __shared__ u16 Vtt[128 * 36];       // [dim][key] natural
    __shared__ u16 Ps[NH][32 * 36];     // per-wave P [q][key] natural
    __shared__ float Mf[32 * 36];       // mask addend [q][key], stride 36

    const int b    = blockIdx.x;
    const int q0   = blockIdx.y * 32;
    const int t    = threadIdx.x;
    const int hh   = t >> 6;
    const int lane = t & 63;
    const int quad = lane >> 4;         // 0..3
    const int c    = lane & 15;
    const int qq   = lane & 31;         // score col (q-row) / A-frag row (key)
    const int hi   = lane >> 5;         // k-slice select for 32x32x16 frags

    const f32x4 zf = {0.f, 0.f, 0.f, 0.f};

    // Q fragment (B operand of swapped score MFMA): full 16-dim head slice
    bf16x8 qf = *(const bf16x8*)&Qb[((size_t)b * NQ + q0 + qq) * 128 +
                                    hh * 16 + hi * 8];

    f32x4 O[2] = {zf, zf};
    float lsum = 0.f;

    // staging indices
    const int skey = t >> 4;            // K: key 0..31, dim octet (t&15)*8
    const int sd0  = (t & 15) * 8;
    const int vdim = t >> 2;            // V: dim 0..127, slot octet (t&3)*8
    const int vs0  = (t & 3) * 8;
    const int mrow = t >> 4;            // M: q-row 0..31, key pair (t&15)*2
    const int mk0  = (t & 15) * 2;

    const u16* Kptr = &Kb[((size_t)b * GS + skey) * 128 + sd0];
    const u16* Vptr = &Vtg[(size_t)b * (128 * 1024) + (size_t)vdim * 1024 + vs0];
    const int* Mptr = &mask[((size_t)b * NQ + q0 + mrow) * GS + mk0];

    int4 kreg = *(const int4*)Kptr;
    int4 vreg = *(const int4*)Vptr;
    int2 mreg = *(const int2*)Mptr;

    for (int g0 = 0; g0 < GS; g0 += 32) {
        __syncthreads();
        *(int4*)&Kt[skey * 136 + sd0] = kreg;
        *(int4*)&Vtt[vdim * 36 + vs0] = vreg;
        f32x2 mm;
        mm.x = mreg.x ? MBIG : 0.f;
        mm.y = mreg.y ? MBIG : 0.f;
        *(f32x2*)&Mf[mrow * 36 + mk0] = mm;
        __syncthreads();

        if (g0 + 32 < GS) {
            Kptr += 32 * 128;  kreg = *(const int4*)Kptr;
            Vptr += 32;        vreg = *(const int4*)Vptr;
            Mptr += 32;        mreg = *(const int2*)Mptr;
        }

        // swapped score: D[key][q], K=16 (head dim), mask addend in C
        bf16x8 kf = *(const bf16x8*)&Kt[qq * 136 + hh * 16 + hi * 8];
        f32x16 c0;
#pragma unroll
        for (int blk = 0; blk < 4; ++blk) {
            f32x4 m = *(const f32x4*)&Mf[qq * 36 + 8 * blk + 4 * hi];
            c0[4 * blk + 0] = m.x;
            c0[4 * blk + 1] = m.y;
            c0[4 * blk + 2] = m.z;
            c0[4 * blk + 3] = m.w;
        }
        f32x16 sc = MFMA32(kf, qf, c0);

        bf16x8 vf = *(const bf16x8*)&Vtt[(hh * 16 + c) * 36 + quad * 8];

        // softmax numerators: raw v_exp_f32; masked -> exactly 0
        float e[16];
#pragma unroll
        for (int r = 0; r < 16; ++r) e[r] = __builtin_amdgcn_exp2f(sc[r]);
        lsum += ((e[0] + e[1]) + (e[2] + e[3])) + ((e[4] + e[5]) + (e[6] + e[7])) +
                (((e[8] + e[9]) + (e[10] + e[11])) + ((e[12] + e[13]) + (e[14] + e[15])));
        // reg r -> key (r&3) + 8*(r>>2) + 4*hi ; pack 4 keys per b64 write
#pragma unroll
        for (int blk = 0; blk < 4; ++blk) {
            int2 pw;
            pw.x = (int)pk2bf(e[4 * blk + 0], e[4 * blk + 1]);
            pw.y = (int)pk2bf(e[4 * blk + 2], e[4 * blk + 3]);
            *(int2*)&Ps[hh][qq * 36 + 8 * blk + 4 * hi] = pw;
        }

        // PV in natural key order
#pragma unroll
        for (int s = 0; s < 2; ++s) {
            bf16x8 pf = *(const bf16x8*)&Ps[hh][(s * 16 + c) * 36 + quad * 8];
            O[s] = MFMA16(pf, vf, O[s]);
        }
    }

    // l-reduction: lane qq holds half-sum for q-row qq; combine halves
    lsum += __shfl_xor(lsum, 32);
    float rlv = (lsum > 0.f) ? 1.f / lsum : 0.f;

    __syncthreads();
    u16* Hs = Kt;
#pragma unroll
    for (int s = 0; s < 2; ++s)
#pragma unroll
        for (int r = 0; r < 4; ++r) {
            float rlq = __shfl(rlv, s * 16 + quad * 4 + r);
            Hs[(s * 16 + quad * 4 + r) * 136 + hh * 16 + c] =
                f2bf(O[s][r] * rlq);
        }
    __syncthreads();

    // fused out-projection: wave hh computes out cols hh*16..+15
    f32x4 oacc[2] = {zf, zf};
#pragma unroll
    for (int kt = 0; kt < 4; ++kt) {
        bf16x8 bfr = *(const bf16x8*)&Wob[(hh * 16 + c) * 128 + kt * 32 + quad * 8];
#pragma unroll
        for (int s = 0; s < 2; ++s) {
            bf16x8 af = *(const bf16x8*)&Hs[(s * 16 + c) * 136 + kt * 32 + quad * 8];
            oacc[s] = MFMA16(af, bfr, oacc[s]);
        }
    }
#pragma unroll
    for (int s = 0; s < 2; ++s)
#pragma unroll
        for (int r = 0; r < 4; ++r)
            out[((size_t)b * NQ + q0 + s * 16 + quad * 4 + r) * 128 + hh * 16 + c] =
                oacc[s][r];
}

extern "C" void kernel_launch(void* const* d_in, const int* in_sizes, int n_in,
                              void* d_out, int out_size, void* d_ws, size_t ws_size,
                              hipStream_t stream) {
    const float* q    = (const float*)d_in[0];
    const float* h    = (const float*)d_in[1];
    const int*   mask = (const int*)d_in[2];
    const float* Wq   = (const float*)d_in[3];
    const float* Wk   = (const float*)d_in[4];
    const float* Wv   = (const float*)d_in[5];
    const float* Wout = (const float*)d_in[6];
    float* out = (float*)d_out;

    const size_t NTOK = (size_t)NB * NQ;     // 32768
    u16* Qb  = (u16*)d_ws;                   // 8 MB each
    u16* Kb  = Qb + NTOK * 128;
    u16* Vtg = Kb + NTOK * 128;              // V transposed per batch (natural)
    u16* Wp  = Vtg + NTOK * 128;             // prepped weights (incl. Wob), 128 KB

    wprep<<<dim3(256), 256, 0, stream>>>(Wq, Wk, Wv, Wout, Wp);
    proj_mfma<<<dim3(256, 3), 256, 0, stream>>>(q, h, Wp, Qb, Kb, Vtg);
    flash_mfma<<<dim3(NB, NQ / 32), 512, 0, stream>>>(Qb, Kb, Vtg, mask,
                                                      Wp + 49152, out);
}

// Round 4
// 275.366 us; speedup vs baseline: 1.1810x; 1.1136x over previous
//
#include <hip/hip_runtime.h>

typedef unsigned short u16;
typedef unsigned int   u32;
typedef short bf16x8 __attribute__((ext_vector_type(8)));
typedef float f32x2  __attribute__((ext_vector_type(2)));
typedef float f32x4  __attribute__((ext_vector_type(4)));
typedef float f32x16 __attribute__((ext_vector_type(16)));

#define NB  32
#define NQ  1024
#define GS  1024
#define NH  8
#define SCQ (0.25f * 1.4426950408889634f)   /* 1/sqrt(16) * log2(e) */
#define MBIG (-1.0e30f)

#define MFMA16(a, b, c) __builtin_amdgcn_mfma_f32_16x16x32_bf16(a, b, c, 0, 0, 0)
#define MFMA32(a, b, c) __builtin_amdgcn_mfma_f32_32x32x16_bf16(a, b, c, 0, 0, 0)

__device__ __forceinline__ u16 f2bf(float f) {  // RNE float->bf16 bits
    u32 u = __float_as_uint(f);
    return (u16)((u + 0x7fffu + ((u >> 16) & 1u)) >> 16);
}
// packed round-half-up: result = bf(a) | bf(b)<<16, 3 VALU ops via v_perm_b32
__device__ __forceinline__ u32 pk2bf(float a, float b) {
    u32 ua = __float_as_uint(a) + 0x8000u;
    u32 ub = __float_as_uint(b) + 0x8000u;
    return __builtin_amdgcn_perm(ub, ua, 0x07060302u);  // bytes [b3 b2 a3 a2]
}

// ---------------------------------------------------------------------------
// Weight prep (256 blocks, 1 elem/thread): Wp[m][i] bf16.
//  m=0..2 (Wq/Wk/Wv [8][128][16]): i = col*128 + k, col=16h+e, k=d; SCQ in m=0.
//  m=3 (Wout [8][16][128]):        i = d*128 + he   (Wob layout for fused out).
// ---------------------------------------------------------------------------
__global__ __launch_bounds__(256) void wprep(const float* __restrict__ Wq,
                                             const float* __restrict__ Wk,
                                             const float* __restrict__ Wv,
                                             const float* __restrict__ Wout,
                                             u16* __restrict__ Wp) {
    int g = blockIdx.x * 256 + threadIdx.x;   // 65536 total
    int m = g >> 14;
    int i = g & 16383;
    const float* src = (m == 0) ? Wq : (m == 1) ? Wk : (m == 2) ? Wv : Wout;
    float sc = (m == 0) ? SCQ : 1.0f;
    float v;
    if (m < 3) { int cc = i >> 7, k = i & 127;  v = src[(cc >> 4) * 2048 + k * 16 + (cc & 15)]; }
    else       { int d  = i >> 7, he = i & 127; v = src[(he >> 4) * 2048 + (he & 15) * 128 + d]; }
    Wp[m * 16384 + i] = f2bf(v * sc);
}

// ---------------------------------------------------------------------------
// MFMA GEMM: C[128x128] = A[128x128] * W^T, K=128 staged once.
// 256 thr = 4 waves; A fp32 -> bf16 in staging; W prepped bf16 (b128 copies).
// Epilogue goes through LDS (reusing As) so ALL global stores are int4:
// MODE 0: bf16 out row-major.
// MODE 2: bf16 out transposed per batch, NATURAL token order:
//         Vt_g[b][col][tb]  (flash stages V tiles by straight int4 copy).
// ---------------------------------------------------------------------------
template <int MODE>
__device__ __forceinline__ void mgemm(const float* __restrict__ Ain,
                                      const u16* __restrict__ Wpm,
                                      u16* __restrict__ outb,
                                      u16* As, u16* Ws, int row0) {
    const int t    = threadIdx.x;
    const int wv   = t >> 6;
    const int lane = t & 63;
    const int quad = lane >> 4;
    const int c    = lane & 15;

#pragma unroll
    for (int g0 = 0; g0 < 2048; g0 += 256) {
        int g = g0 + t;
        int row = g >> 4, k0 = (g & 15) * 8;
        const float4* ap = (const float4*)&Ain[(size_t)(row0 + row) * 128 + k0];
        float4 a0 = ap[0], a1 = ap[1];
        int4 pk;
        pk.x = (int)pk2bf(a0.x, a0.y);
        pk.y = (int)pk2bf(a0.z, a0.w);
        pk.z = (int)pk2bf(a1.x, a1.y);
        pk.w = (int)pk2bf(a1.z, a1.w);
        *(int4*)&As[row * 136 + k0] = pk;
    }
#pragma unroll
    for (int g0 = 0; g0 < 2048; g0 += 256) {
        int g = g0 + t;
        int cc = g >> 4, k0 = (g & 15) * 8;
        *(int4*)&Ws[cc * 136 + k0] = *(const int4*)&Wpm[cc * 128 + k0];
    }
    __syncthreads();

    const f32x4 zf = {0.f, 0.f, 0.f, 0.f};
    f32x4 acc[2][8];
#pragma unroll
    for (int s = 0; s < 2; ++s)
#pragma unroll
        for (int j = 0; j < 8; ++j) acc[s][j] = zf;

#pragma unroll
    for (int kt = 0; kt < 4; ++kt) {
        bf16x8 af0 = *(const bf16x8*)&As[(wv * 32 + c) * 136 + kt * 32 + quad * 8];
        bf16x8 af1 = *(const bf16x8*)&As[(wv * 32 + 16 + c) * 136 + kt * 32 + quad * 8];
#pragma unroll
        for (int j = 0; j < 8; ++j) {
            bf16x8 bfr = *(const bf16x8*)&Ws[(j * 16 + c) * 136 + kt * 32 + quad * 8];
            acc[0][j] = MFMA16(af0, bfr, acc[0][j]);
            acc[1][j] = MFMA16(af1, bfr, acc[1][j]);
        }
    }

    // ---- epilogue via LDS: scatter bf16 into As, then coalesced int4 out ----
    __syncthreads();                 // all As/Ws reads complete
    u16* Os = As;                    // reuse 128x136 u16
#pragma unroll
    for (int s = 0; s < 2; ++s)
#pragma unroll
        for (int j = 0; j < 8; ++j)
#pragma unroll
            for (int r = 0; r < 4; ++r) {
                int lrow = wv * 32 + s * 16 + quad * 4 + r;
                int col  = j * 16 + c;
                u16 v = f2bf(acc[s][j][r]);
                if (MODE == 0) {
                    Os[lrow * 136 + col] = v;
                } else {
                    Os[col * 136 + lrow] = v;   // natural token order
                }
            }
    __syncthreads();

    if (MODE == 0) {
#pragma unroll
        for (int it = 0; it < 8; ++it) {
            int chunk = it * 256 + t;           // 2048 int4 chunks
            int lrow = chunk >> 4, c0 = (chunk & 15) * 8;
            *(int4*)&outb[(size_t)(row0 + lrow) * 128 + c0] =
                *(const int4*)&Os[lrow * 136 + c0];
        }
    } else {
        int bI = row0 >> 10, tb0 = row0 & 1023; // 128-aligned
#pragma unroll
        for (int it = 0; it < 8; ++it) {
            int chunk = it * 256 + t;
            int col = chunk >> 4, t0 = (chunk & 15) * 8;
            *(int4*)&outb[(size_t)bI * (128 * 1024) + (size_t)col * 1024 + tb0 + t0] =
                *(const int4*)&Os[col * 136 + t0];
        }
    }
}

__global__ __launch_bounds__(256, 2) void proj_mfma(const float* __restrict__ q,
                                                    const float* __restrict__ h,
                                                    const u16* __restrict__ Wp,
                                                    u16* __restrict__ Qb,
                                                    u16* __restrict__ Kb,
                                                    u16* __restrict__ Vtg) {
    __shared__ u16 As[128 * 136];
    __shared__ u16 Ws[128 * 136];
    int row0 = blockIdx.x * 128;
    if (blockIdx.y == 0)      mgemm<0>(q, Wp,         Qb,  As, Ws, row0);
    else if (blockIdx.y == 1) mgemm<0>(h, Wp + 16384, Kb,  As, Ws, row0);
    else                      mgemm<2>(h, Wp + 32768, Vtg, As, Ws, row0);
}

// ---------------------------------------------------------------------------
// MFMA flash attention + fused out-projection, v4: KVBLK=64.
// Round-3 counters: MfmaUtil 5%, VALUBusy 26%, HBM 10% -> latency/sync bound
// (~85% of issue slots idle). v4 doubles work per barrier pair: stage 64
// keys/slots/mask-cols per iteration (16 iters instead of 32), then TWO
// independent score->exp->P->PV chains. Halves barriers, gives the one-tile
// global prefetch 2x compute time to land, chunk1 VALU overlaps chunk0 LDS
// latency. LDS 81408 B -> 2 blocks/CU (matches measured occupancy anyway).
// ---------------------------------------------------------------------------
__global__ __launch_bounds__(512, 4) void flash_mfma(const u16* __restrict__ Qb,
                                                     const u16* __restrict__ Kb,
                                                     const u16* __restrict__ Vtg,
                                                     const int* __restrict__ mask,
                                                     const u16* __restrict__ Wob,
                                                     float* __restrict__ out) {
    __shared__ u16 Kt[64 * 136];        // [key][dim]; rows 0..31 reused as Hs
    __shared__ u16 Vtt[128 * 72];       // [dim][slot 0..63]
    __shared__ u16 Ps[NH][64 * 36];     // per-wave P, chunk ks at ks*1152
    __shared__ float Mf[32 * 68];       // mask addend [q][key 0..63]

    const int b    = blockIdx.x;
    const int q0   = blockIdx.y * 32;
    const int t    = threadIdx.x;
    const int hh   = t >> 6;
    const int lane = t & 63;
    const int quad = lane >> 4;         // 0..3
    const int c    = lane & 15;
    const int qq   = lane & 31;         // score col (q-row) / A-frag row (key)
    const int hi   = lane >> 5;         // k-slice select for 32x32x16 frags

    const f32x4 zf = {0.f, 0.f, 0.f, 0.f};

    // Q fragment (B operand of swapped score MFMA): full 16-dim head slice
    bf16x8 qf = *(const bf16x8*)&Qb[((size_t)b * NQ + q0 + qq) * 128 +
                                    hh * 16 + hi * 8];

    f32x4 O[2] = {zf, zf};
    float lsum = 0.f;

    // staging indices
    const int skey = t >> 4;            // K: key 0..31 (+32), dim octet (t&15)*8
    const int sd0  = (t & 15) * 8;
    const int vdim = t >> 2;            // V: dim 0..127, slot octet (t&3)*8 (+32)
    const int vs0  = (t & 3) * 8;
    const int mrow = t >> 4;            // M: q-row 0..31, key pair (t&15)*2 (+32)
    const int mk0  = (t & 15) * 2;

    const u16* Kptr = &Kb[((size_t)b * GS + skey) * 128 + sd0];
    const u16* Vptr = &Vtg[(size_t)b * (128 * 1024) + (size_t)vdim * 1024 + vs0];
    const int* Mptr = &mask[((size_t)b * NQ + q0 + mrow) * GS + mk0];

    int4 kreg0 = *(const int4*)Kptr;
    int4 kreg1 = *(const int4*)(Kptr + 32 * 128);
    int4 vreg0 = *(const int4*)Vptr;
    int4 vreg1 = *(const int4*)(Vptr + 32);
    int2 mreg0 = *(const int2*)Mptr;
    int2 mreg1 = *(const int2*)(Mptr + 32);

    for (int g0 = 0; g0 < GS; g0 += 64) {
        __syncthreads();
        *(int4*)&Kt[skey * 136 + sd0]        = kreg0;
        *(int4*)&Kt[(32 + skey) * 136 + sd0] = kreg1;
        *(int4*)&Vtt[vdim * 72 + vs0]        = vreg0;
        *(int4*)&Vtt[vdim * 72 + 32 + vs0]   = vreg1;
        f32x2 mm0, mm1;
        mm0.x = mreg0.x ? MBIG : 0.f;
        mm0.y = mreg0.y ? MBIG : 0.f;
        mm1.x = mreg1.x ? MBIG : 0.f;
        mm1.y = mreg1.y ? MBIG : 0.f;
        *(f32x2*)&Mf[mrow * 68 + mk0]      = mm0;
        *(f32x2*)&Mf[mrow * 68 + 32 + mk0] = mm1;
        __syncthreads();

        if (g0 + 64 < GS) {
            Kptr += 64 * 128;
            kreg0 = *(const int4*)Kptr;
            kreg1 = *(const int4*)(Kptr + 32 * 128);
            Vptr += 64;
            vreg0 = *(const int4*)Vptr;
            vreg1 = *(const int4*)(Vptr + 32);
            Mptr += 64;
            mreg0 = *(const int2*)Mptr;
            mreg1 = *(const int2*)(Mptr + 32);
        }

        // two independent swapped-score chains: D[key][q], K=16 head dim
        bf16x8 kf0 = *(const bf16x8*)&Kt[qq * 136 + hh * 16 + hi * 8];
        bf16x8 kf1 = *(const bf16x8*)&Kt[(32 + qq) * 136 + hh * 16 + hi * 8];
        bf16x8 vf0 = *(const bf16x8*)&Vtt[(hh * 16 + c) * 72 + quad * 8];
        bf16x8 vf1 = *(const bf16x8*)&Vtt[(hh * 16 + c) * 72 + 32 + quad * 8];
        f32x16 c0, c1;
#pragma unroll
        for (int blk = 0; blk < 4; ++blk) {
            f32x4 m0 = *(const f32x4*)&Mf[qq * 68 + 8 * blk + 4 * hi];
            f32x4 m1 = *(const f32x4*)&Mf[qq * 68 + 32 + 8 * blk + 4 * hi];
            c0[4 * blk + 0] = m0.x;  c0[4 * blk + 1] = m0.y;
            c0[4 * blk + 2] = m0.z;  c0[4 * blk + 3] = m0.w;
            c1[4 * blk + 0] = m1.x;  c1[4 * blk + 1] = m1.y;
            c1[4 * blk + 2] = m1.z;  c1[4 * blk + 3] = m1.w;
        }
        f32x16 sc0 = MFMA32(kf0, qf, c0);
        f32x16 sc1 = MFMA32(kf1, qf, c1);

        // chunk 0 softmax numerators + P write
        float e0[16];
#pragma unroll
        for (int r = 0; r < 16; ++r) e0[r] = __builtin_amdgcn_exp2f(sc0[r]);
        lsum += ((e0[0] + e0[1]) + (e0[2] + e0[3])) + ((e0[4] + e0[5]) + (e0[6] + e0[7])) +
                (((e0[8] + e0[9]) + (e0[10] + e0[11])) + ((e0[12] + e0[13]) + (e0[14] + e0[15])));
#pragma unroll
        for (int blk = 0; blk < 4; ++blk) {
            int2 pw;
            pw.x = (int)pk2bf(e0[4 * blk + 0], e0[4 * blk + 1]);
            pw.y = (int)pk2bf(e0[4 * blk + 2], e0[4 * blk + 3]);
            *(int2*)&Ps[hh][qq * 36 + 8 * blk + 4 * hi] = pw;
        }

        // chunk 1 softmax numerators + P write (overlaps chunk0 LDS latency)
        float e1[16];
#pragma unroll
        for (int r = 0; r < 16; ++r) e1[r] = __builtin_amdgcn_exp2f(sc1[r]);
        lsum += ((e1[0] + e1[1]) + (e1[2] + e1[3])) + ((e1[4] + e1[5]) + (e1[6] + e1[7])) +
                (((e1[8] + e1[9]) + (e1[10] + e1[11])) + ((e1[12] + e1[13]) + (e1[14] + e1[15])));
#pragma unroll
        for (int blk = 0; blk < 4; ++blk) {
            int2 pw;
            pw.x = (int)pk2bf(e1[4 * blk + 0], e1[4 * blk + 1]);
            pw.y = (int)pk2bf(e1[4 * blk + 2], e1[4 * blk + 3]);
            *(int2*)&Ps[hh][1152 + qq * 36 + 8 * blk + 4 * hi] = pw;
        }

        // PV chunk 0 then chunk 1
#pragma unroll
        for (int s = 0; s < 2; ++s) {
            bf16x8 pf = *(const bf16x8*)&Ps[hh][(s * 16 + c) * 36 + quad * 8];
            O[s] = MFMA16(pf, vf0, O[s]);
        }
#pragma unroll
        for (int s = 0; s < 2; ++s) {
            bf16x8 pf = *(const bf16x8*)&Ps[hh][1152 + (s * 16 + c) * 36 + quad * 8];
            O[s] = MFMA16(pf, vf1, O[s]);
        }
    }

    // l-reduction: lane qq holds half-sum for q-row qq; combine halves
    lsum += __shfl_xor(lsum, 32);
    float rlv = (lsum > 0.f) ? 1.f / lsum : 0.f;

    __syncthreads();
    u16* Hs = Kt;
#pragma unroll
    for (int s = 0; s < 2; ++s)
#pragma unroll
        for (int r = 0; r < 4; ++r) {
            float rlq = __shfl(rlv, s * 16 + quad * 4 + r);
            Hs[(s * 16 + quad * 4 + r) * 136 + hh * 16 + c] =
                f2bf(O[s][r] * rlq);
        }
    __syncthreads();

    // fused out-projection: wave hh computes out cols hh*16..+15
    f32x4 oacc[2] = {zf, zf};
#pragma unroll
    for (int kt = 0; kt < 4; ++kt) {
        bf16x8 bfr = *(const bf16x8*)&Wob[(hh * 16 + c) * 128 + kt * 32 + quad * 8];
#pragma unroll
        for (int s = 0; s < 2; ++s) {
            bf16x8 af = *(const bf16x8*)&Hs[(s * 16 + c) * 136 + kt * 32 + quad * 8];
            oacc[s] = MFMA16(af, bfr, oacc[s]);
        }
    }
#pragma unroll
    for (int s = 0; s < 2; ++s)
#pragma unroll
        for (int r = 0; r < 4; ++r)
            out[((size_t)b * NQ + q0 + s * 16 + quad * 4 + r) * 128 + hh * 16 + c] =
                oacc[s][r];
}

extern "C" void kernel_launch(void* const* d_in, const int* in_sizes, int n_in,
                              void* d_out, int out_size, void* d_ws, size_t ws_size,
                              hipStream_t stream) {
    const float* q    = (const float*)d_in[0];
    const float* h    = (const float*)d_in[1];
    const int*   mask = (const int*)d_in[2];
    const float* Wq   = (const float*)d_in[3];
    const float* Wk   = (const float*)d_in[4];
    const float* Wv   = (const float*)d_in[5];
    const float* Wout = (const float*)d_in[6];
    float* out = (float*)d_out;

    const size_t NTOK = (size_t)NB * NQ;     // 32768
    u16* Qb  = (u16*)d_ws;                   // 8 MB each
    u16* Kb  = Qb + NTOK * 128;
    u16* Vtg = Kb + NTOK * 128;              // V transposed per batch (natural)
    u16* Wp  = Vtg + NTOK * 128;             // prepped weights (incl. Wob), 128 KB

    wprep<<<dim3(256), 256, 0, stream>>>(Wq, Wk, Wv, Wout, Wp);
    proj_mfma<<<dim3(256, 3), 256, 0, stream>>>(q, h, Wp, Qb, Kb, Vtg);
    flash_mfma<<<dim3(NB, NQ / 32), 512, 0, stream>>>(Qb, Kb, Vtg, mask,
                                                      Wp + 49152, out);
}